// Round 5
// baseline (2705.871 us; speedup 1.0000x reference)
//
#include <hip/hip_runtime.h>
#include <hip/hip_bf16.h>

#define D      64
#define HID    36
#define IN_DIM 192
#define NPB    64        // nodes per bucket (node >> 6)
#define ROWP   129       // padded LDS row: 128 features + 1 (bank spread)
#define MAXNB  2048      // max buckets (n_nodes <= 131072)
#define CHUNK  4096      // endpoint records per partition block

// ---------------------------------------------------------------------------
__global__ void zero_ws_kernel(float4* __restrict__ p, long n4) {
    long i = (long)blockIdx.x * blockDim.x + threadIdx.x;
    long stride = (long)gridDim.x * blockDim.x;
    float4 z = make_float4(0.f, 0.f, 0.f, 0.f);
    for (; i < n4; i += stride) p[i] = z;
}

// FALLBACK: R0 atomic scatter
__global__ __launch_bounds__(256) void scatter_kernel(
    const float* __restrict__ edges,
    const int* __restrict__ senders,
    const int* __restrict__ receivers,
    float* __restrict__ sent,
    float* __restrict__ recv,
    long total)
{
    long i = (long)blockIdx.x * blockDim.x + threadIdx.x;
    if (i >= total) return;
    long e = i >> 6;
    int  d = (int)(i & 63);
    float v = edges[i];
    unsafeAtomicAdd(&sent[(long)senders[e] * D + d], v);
    unsafeAtomicAdd(&recv[(long)receivers[e] * D + d], v);
}

// ---------------------------------------------------------------------------
// K_a: per-block bucket histogram (LDS atomics, non-returning)
// record i in [0,2E): i<E -> (edge=i, dir=0, node=senders[i])
//                     else  (edge=i-E, dir=1, node=receivers[i-E])
// ---------------------------------------------------------------------------
__global__ __launch_bounds__(256) void count_kernel(
    const int* __restrict__ senders,
    const int* __restrict__ receivers,
    int* __restrict__ counts,          // [nblocks][NB]
    int NB, long E, long total_items)
{
    __shared__ int hist[MAXNB];
    for (int b = threadIdx.x; b < NB; b += 256) hist[b] = 0;
    __syncthreads();

    long start = (long)blockIdx.x * CHUNK;
    long end = start + CHUNK; if (end > total_items) end = total_items;
    for (long i = start + threadIdx.x; i < end; i += 256) {
        int node = (i < E) ? senders[i] : receivers[i - E];
        atomicAdd(&hist[node >> 6], 1);
    }
    __syncthreads();
    int* row = counts + (long)blockIdx.x * NB;
    for (int b = threadIdx.x; b < NB; b += 256) row[b] = hist[b];
}

// K_b1: per-bucket column exclusive scan over blocks
__global__ __launch_bounds__(256) void colscan_kernel(
    int* __restrict__ counts, int* __restrict__ tot, int NB, int nblocks)
{
    int b = blockIdx.x * 256 + threadIdx.x;
    if (b >= NB) return;
    int run = 0;
#pragma unroll 4
    for (int blk = 0; blk < nblocks; ++blk) {
        long idx = (long)blk * NB + b;
        int c = counts[idx];
        counts[idx] = run;
        run += c;
    }
    tot[b] = run;
}

// K_b2: exclusive scan of tot[NB] -> base[NB] (single block)
__global__ __launch_bounds__(1024) void basescan_kernel(
    const int* __restrict__ tot, int* __restrict__ base, int NB)
{
    __shared__ int sA[2][MAXNB];
    int t = threadIdx.x;
    sA[0][t]        = (t < NB) ? tot[t] : 0;
    sA[0][t + 1024] = (t + 1024 < NB) ? tot[t + 1024] : 0;
    __syncthreads();
    int src = 0;
    for (int off = 1; off < MAXNB; off <<= 1) {
        int dst = src ^ 1;
        int i0 = t, i1 = t + 1024;
        sA[dst][i0] = sA[src][i0] + ((i0 >= off) ? sA[src][i0 - off] : 0);
        sA[dst][i1] = sA[src][i1] + ((i1 >= off) ? sA[src][i1 - off] : 0);
        src = dst;
        __syncthreads();
    }
    if (t < NB)        base[t]        = (t == 0) ? 0 : sA[src][t - 1];
    if (t + 1024 < NB) base[t + 1024] = sA[src][t + 1023];
}

// K_c: place records grouped by bucket. rec = edge<<7 | dir<<6 | node_lo
__global__ __launch_bounds__(256) void scatter_ids_kernel(
    const int* __restrict__ senders,
    const int* __restrict__ receivers,
    const int* __restrict__ counts,
    const int* __restrict__ base,
    unsigned* __restrict__ pool,
    int NB, long E, long total_items)
{
    __shared__ int cursor[MAXNB];
    const int* row = counts + (long)blockIdx.x * NB;
    for (int b = threadIdx.x; b < NB; b += 256) cursor[b] = row[b] + base[b];
    __syncthreads();

    long start = (long)blockIdx.x * CHUNK;
    long end = start + CHUNK; if (end > total_items) end = total_items;
    for (long i = start + threadIdx.x; i < end; i += 256) {
        int dir, node; long edge;
        if (i < E) { dir = 0; edge = i;     node = senders[i]; }
        else       { dir = 1; edge = i - E; node = receivers[i - E]; }
        int b = node >> 6;
        int pos = atomicAdd(&cursor[b], 1);
        pool[pos] = ((unsigned)edge << 7) | ((unsigned)dir << 6) | (unsigned)(node & 63);
    }
}

// ---------------------------------------------------------------------------
// K_d: one block per bucket. LDS accum [64 nodes][129] f32 (pad -> 32 banks).
// Lane layout: grp = lane>>4 owns one record, f4 = (lane&15)*4 feature quad.
// Hot loop is lgkm-free on the address path: pool ids read from global
// (16-lane broadcast dword), edge rows as float4 (256B/group), ds_add_f32
// fire-and-forget. x2 manual unroll for VMEM in flight.
// ---------------------------------------------------------------------------
__global__ __launch_bounds__(256) void accum_kernel(
    const float* __restrict__ edges,
    const unsigned* __restrict__ pool,
    const int* __restrict__ base,
    const int* __restrict__ tot,
    float* __restrict__ sent,
    float* __restrict__ recv,
    int n_nodes)
{
    __shared__ float accum[NPB][ROWP];     // 33 KB
    int tid = threadIdx.x;
    for (int i = tid; i < NPB * ROWP; i += 256) ((float*)accum)[i] = 0.f;
    __syncthreads();

    int b = blockIdx.x;
    int start = base[b];
    int cnt   = tot[b];
    int end   = start + cnt;

    int wave = tid >> 6, lane = tid & 63;
    int grp = lane >> 4;             // record slot 0..3
    int f4  = (lane & 15) * 4;       // feature quad

    // contiguous per-wave sub-range
    int per = (cnt + 3) >> 2;
    int ws = start + wave * per;
    int we = ws + per; if (we > end) we = end;

    int i = ws;
    for (; i + 8 <= we; i += 8) {
        unsigned rA = pool[i + grp];
        unsigned rB = pool[i + 4 + grp];
        float4 vA = *reinterpret_cast<const float4*>(edges + (long)(rA >> 7) * D + f4);
        float4 vB = *reinterpret_cast<const float4*>(edges + (long)(rB >> 7) * D + f4);
        float* pa = &accum[rA & 63][((rA >> 6) & 1) * D + f4];
        atomicAdd(pa + 0, vA.x);
        atomicAdd(pa + 1, vA.y);
        atomicAdd(pa + 2, vA.z);
        atomicAdd(pa + 3, vA.w);
        float* pb = &accum[rB & 63][((rB >> 6) & 1) * D + f4];
        atomicAdd(pb + 0, vB.x);
        atomicAdd(pb + 1, vB.y);
        atomicAdd(pb + 2, vB.z);
        atomicAdd(pb + 3, vB.w);
    }
    for (; i < we; i += 4) {
        if (i + grp < we) {
            unsigned r = pool[i + grp];
            float4 v = *reinterpret_cast<const float4*>(edges + (long)(r >> 7) * D + f4);
            float* pa = &accum[r & 63][((r >> 6) & 1) * D + f4];
            atomicAdd(pa + 0, v.x);
            atomicAdd(pa + 1, v.y);
            atomicAdd(pa + 2, v.z);
            atomicAdd(pa + 3, v.w);
        }
    }
    __syncthreads();

    int node0 = b * NPB;
    for (int t = tid; t < NPB * D; t += 256) {
        int nl = t >> 6, k = t & 63;
        int node = node0 + nl;
        if (node < n_nodes) {
            sent[(long)node * D + k] = accum[nl][k];
            recv[(long)node * D + k] = accum[nl][D + k];
        }
    }
}

// ---------------------------------------------------------------------------
// per-node MLP (exact f32)
// ---------------------------------------------------------------------------
__global__ __launch_bounds__(256) void mlp_kernel(
    const float* __restrict__ nodes,
    const float* __restrict__ sent,
    const float* __restrict__ recv,
    const float* __restrict__ W1,
    const float* __restrict__ b1,
    const float* __restrict__ W2,
    const float* __restrict__ b2,
    float* __restrict__ out,
    int n)
{
    __shared__ float sW1[IN_DIM * HID];
    __shared__ float sb1[HID];
    __shared__ float sW2[HID * 2];
    __shared__ float sb2[2];

    for (int t = threadIdx.x; t < IN_DIM * HID; t += blockDim.x) sW1[t] = W1[t];
    if (threadIdx.x < HID)     sb1[threadIdx.x] = b1[threadIdx.x];
    if (threadIdx.x < HID * 2) sW2[threadIdx.x] = W2[threadIdx.x];
    if (threadIdx.x < 2)       sb2[threadIdx.x] = b2[threadIdx.x];
    __syncthreads();

    int node = blockIdx.x * blockDim.x + threadIdx.x;
    if (node >= n) return;

    float acc[HID];
#pragma unroll
    for (int j = 0; j < HID; ++j) acc[j] = sb1[j];

#pragma unroll
    for (int part = 0; part < 3; ++part) {
        const float* f = (part == 0 ? nodes : (part == 1 ? sent : recv)) + (long)node * D;
        const float* w = sW1 + part * D * HID;
        for (int k = 0; k < D; k += 4) {
            float4 fv = *reinterpret_cast<const float4*>(f + k);
#pragma unroll
            for (int j = 0; j < HID; ++j) {
                acc[j] += fv.x * w[(k + 0) * HID + j];
                acc[j] += fv.y * w[(k + 1) * HID + j];
                acc[j] += fv.z * w[(k + 2) * HID + j];
                acc[j] += fv.w * w[(k + 3) * HID + j];
            }
        }
    }

    float o0 = sb2[0], o1 = sb2[1];
#pragma unroll
    for (int j = 0; j < HID; ++j) {
        float h = fmaxf(acc[j], 0.f);
        o0 += h * sW2[j * 2 + 0];
        o1 += h * sW2[j * 2 + 1];
    }
    reinterpret_cast<float2*>(out)[node] = make_float2(o0, o1);
}

// ---------------------------------------------------------------------------
extern "C" void kernel_launch(void* const* d_in, const int* in_sizes, int n_in,
                              void* d_out, int out_size, void* d_ws, size_t ws_size,
                              hipStream_t stream) {
    const float* nodes     = (const float*)d_in[0];
    const float* edges     = (const float*)d_in[1];
    const int*   senders   = (const int*)d_in[2];
    const int*   receivers = (const int*)d_in[3];
    const float* W1        = (const float*)d_in[4];
    const float* b1        = (const float*)d_in[5];
    const float* W2        = (const float*)d_in[6];
    const float* b2        = (const float*)d_in[7];
    float* out = (float*)d_out;

    const int  n_nodes = in_sizes[0] / D;      // 100,000
    const long E       = in_sizes[2];          // 3,200,000
    const long total_items = 2 * E;            // 6.4M endpoint records

    const int NB      = (n_nodes + NPB - 1) / NPB;                 // 1563
    const int nblocks = (int)((total_items + CHUNK - 1) / CHUNK);  // 1563

    const size_t sz_sent = (size_t)n_nodes * D * sizeof(float);    // 25.6 MB
    const size_t sz_pool = (size_t)total_items * sizeof(unsigned); // 25.6 MB
    const size_t sz_nb   = (size_t)MAXNB * sizeof(int);
    const size_t need    = 2 * sz_sent + sz_pool + 2 * sz_nb;
    const size_t sz_counts = (size_t)nblocks * NB * sizeof(int);   // 9.8 MB

    char* wp = (char*)d_ws;
    float*    sent = (float*)wp;            wp += sz_sent;
    float*    recv = (float*)wp;            wp += sz_sent;
    unsigned* pool = (unsigned*)wp;         wp += sz_pool;
    int*      tot  = (int*)wp;              wp += sz_nb;
    int*      base = (int*)wp;
    int*      counts = (int*)sent;          // aliased; lifetime ends at K_c

    if (ws_size < need || NB > MAXNB || sz_counts > sz_sent) {
        long n4 = (long)n_nodes * D * 2 / 4;
        zero_ws_kernel<<<2048, 256, 0, stream>>>((float4*)d_ws, n4);
        long total = E * D;
        scatter_kernel<<<(int)((total + 255) / 256), 256, 0, stream>>>(
            edges, senders, receivers, sent, recv, total);
        mlp_kernel<<<(n_nodes + 255) / 256, 256, 0, stream>>>(
            nodes, sent, recv, W1, b1, W2, b2, out, n_nodes);
        return;
    }

    count_kernel<<<nblocks, 256, 0, stream>>>(senders, receivers, counts,
                                              NB, E, total_items);
    colscan_kernel<<<(NB + 255) / 256, 256, 0, stream>>>(counts, tot, NB, nblocks);
    basescan_kernel<<<1, 1024, 0, stream>>>(tot, base, NB);
    scatter_ids_kernel<<<nblocks, 256, 0, stream>>>(senders, receivers, counts,
                                                    base, pool, NB, E, total_items);
    accum_kernel<<<NB, 256, 0, stream>>>(edges, pool, base, tot,
                                         sent, recv, n_nodes);
    mlp_kernel<<<(n_nodes + 255) / 256, 256, 0, stream>>>(
        nodes, sent, recv, W1, b1, W2, b2, out, n_nodes);
}

// Round 6
// 728.108 us; speedup vs baseline: 3.7163x; 3.7163x over previous
//
#include <hip/hip_runtime.h>
#include <hip/hip_bf16.h>

#define D      64
#define HID    36
#define IN_DIM 192
#define NPB    64        // nodes per bucket (node >> 6)
#define MAXNB  2048      // max buckets (n_nodes <= 131072)
#define CHUNK  4096      // endpoint records per partition block

// ---------------------------------------------------------------------------
__global__ void zero_ws_kernel(float4* __restrict__ p, long n4) {
    long i = (long)blockIdx.x * blockDim.x + threadIdx.x;
    long stride = (long)gridDim.x * blockDim.x;
    float4 z = make_float4(0.f, 0.f, 0.f, 0.f);
    for (; i < n4; i += stride) p[i] = z;
}

// FALLBACK: R0 atomic scatter
__global__ __launch_bounds__(256) void scatter_kernel(
    const float* __restrict__ edges,
    const int* __restrict__ senders,
    const int* __restrict__ receivers,
    float* __restrict__ sent,
    float* __restrict__ recv,
    long total)
{
    long i = (long)blockIdx.x * blockDim.x + threadIdx.x;
    if (i >= total) return;
    long e = i >> 6;
    int  d = (int)(i & 63);
    float v = edges[i];
    unsafeAtomicAdd(&sent[(long)senders[e] * D + d], v);
    unsafeAtomicAdd(&recv[(long)receivers[e] * D + d], v);
}

// ---------------------------------------------------------------------------
// K_a: per-block bucket histogram.
// record i in [0,2E): i<E -> (edge=i, dir=0, node=senders[i])
//                     else  (edge=i-E, dir=1, node=receivers[i-E])
// ---------------------------------------------------------------------------
__global__ __launch_bounds__(256) void count_kernel(
    const int* __restrict__ senders,
    const int* __restrict__ receivers,
    int* __restrict__ counts,          // [nblocks][NB]
    int NB, long E, long total_items)
{
    __shared__ int hist[MAXNB];
    for (int b = threadIdx.x; b < NB; b += 256) hist[b] = 0;
    __syncthreads();

    long start = (long)blockIdx.x * CHUNK;
    long end = start + CHUNK; if (end > total_items) end = total_items;
    for (long i = start + threadIdx.x; i < end; i += 256) {
        int node = (i < E) ? senders[i] : receivers[i - E];
        atomicAdd(&hist[node >> 6], 1);
    }
    __syncthreads();
    int* row = counts + (long)blockIdx.x * NB;
    for (int b = threadIdx.x; b < NB; b += 256) row[b] = hist[b];
}

// K_b1: per-bucket column exclusive scan over blocks
__global__ __launch_bounds__(256) void colscan_kernel(
    int* __restrict__ counts, int* __restrict__ tot, int NB, int nblocks)
{
    int b = blockIdx.x * 256 + threadIdx.x;
    if (b >= NB) return;
    int run = 0;
#pragma unroll 4
    for (int blk = 0; blk < nblocks; ++blk) {
        long idx = (long)blk * NB + b;
        int c = counts[idx];
        counts[idx] = run;
        run += c;
    }
    tot[b] = run;
}

// K_b2: exclusive scan of tot[NB] -> base[NB] (single block)
__global__ __launch_bounds__(1024) void basescan_kernel(
    const int* __restrict__ tot, int* __restrict__ base, int NB)
{
    __shared__ int sA[2][MAXNB];
    int t = threadIdx.x;
    sA[0][t]        = (t < NB) ? tot[t] : 0;
    sA[0][t + 1024] = (t + 1024 < NB) ? tot[t + 1024] : 0;
    __syncthreads();
    int src = 0;
    for (int off = 1; off < MAXNB; off <<= 1) {
        int dst = src ^ 1;
        int i0 = t, i1 = t + 1024;
        sA[dst][i0] = sA[src][i0] + ((i0 >= off) ? sA[src][i0 - off] : 0);
        sA[dst][i1] = sA[src][i1] + ((i1 >= off) ? sA[src][i1 - off] : 0);
        src = dst;
        __syncthreads();
    }
    if (t < NB)        base[t]        = (t == 0) ? 0 : sA[src][t - 1];
    if (t + 1024 < NB) base[t + 1024] = sA[src][t + 1023];
}

// K_c: place records grouped by bucket. rec = edge<<7 | dir<<6 | node_lo
__global__ __launch_bounds__(256) void scatter_ids_kernel(
    const int* __restrict__ senders,
    const int* __restrict__ receivers,
    const int* __restrict__ counts,
    const int* __restrict__ base,
    unsigned* __restrict__ pool,
    int NB, long E, long total_items)
{
    __shared__ int cursor[MAXNB];
    const int* row = counts + (long)blockIdx.x * NB;
    for (int b = threadIdx.x; b < NB; b += 256) cursor[b] = row[b] + base[b];
    __syncthreads();

    long start = (long)blockIdx.x * CHUNK;
    long end = start + CHUNK; if (end > total_items) end = total_items;
    for (long i = start + threadIdx.x; i < end; i += 256) {
        int dir, node; long edge;
        if (i < E) { dir = 0; edge = i;     node = senders[i]; }
        else       { dir = 1; edge = i - E; node = receivers[i - E]; }
        int b = node >> 6;
        int pos = atomicAdd(&cursor[b], 1);
        pool[pos] = ((unsigned)edge << 7) | ((unsigned)dir << 6) | (unsigned)(node & 63);
    }
}

// ---------------------------------------------------------------------------
// K_e: per-bucket counting sort by key = (node_lo<<1)|dir (128 keys).
// Produces pool2 (edge ids, node-sorted within bucket) and per-node segment
// info seg[node] = {sent_start, sent_cnt, recv_start, recv_cnt}.
// Only tiny LDS counters; records re-read from global (no LDS capacity risk).
// ---------------------------------------------------------------------------
__global__ __launch_bounds__(256) void sort_bucket_kernel(
    const unsigned* __restrict__ pool,
    const int* __restrict__ base,
    const int* __restrict__ tot,
    unsigned* __restrict__ pool2,
    int4* __restrict__ seg,
    int n_nodes)
{
    __shared__ int hist[128], off[128], cursor[128], tmp[128];
    int b = blockIdx.x, tid = threadIdx.x;
    int bstart = base[b], cnt = tot[b];

    if (tid < 128) hist[tid] = 0;
    __syncthreads();

    for (int i = tid; i < cnt; i += 256) {
        unsigned r = pool[bstart + i];
        int key = ((r & 63) << 1) | ((r >> 6) & 1);
        atomicAdd(&hist[key], 1);
    }
    __syncthreads();

    // exclusive scan of hist -> off (Hillis-Steele over 128)
    if (tid < 128) tmp[tid] = hist[tid];
    __syncthreads();
    for (int d = 1; d < 128; d <<= 1) {
        int v = 0;
        if (tid < 128) v = (tid >= d) ? tmp[tid - d] : 0;
        __syncthreads();
        if (tid < 128) tmp[tid] += v;
        __syncthreads();
    }
    if (tid < 128) {
        int o = tmp[tid] - hist[tid];
        off[tid] = o;
        cursor[tid] = o;
    }
    __syncthreads();

    if (tid < 64) {
        int node = b * NPB + tid;
        if (node < n_nodes) {
            seg[node] = make_int4(bstart + off[tid * 2],     hist[tid * 2],
                                  bstart + off[tid * 2 + 1], hist[tid * 2 + 1]);
        }
    }

    for (int i = tid; i < cnt; i += 256) {
        unsigned r = pool[bstart + i];
        int key = ((r & 63) << 1) | ((r >> 6) & 1);
        int pos = atomicAdd(&cursor[key], 1);
        pool2[bstart + pos] = r >> 7;          // bare edge id
    }
}

// ---------------------------------------------------------------------------
// K_f: gather. One wave per node, lane = feature. Register accumulation only:
// broadcast id loads + coalesced 256B edge-row loads, vmcnt-only waits.
// Writes zeros for zero-degree nodes (no pre-zero pass needed).
// ---------------------------------------------------------------------------
__global__ __launch_bounds__(256) void gather_kernel(
    const float* __restrict__ edges,
    const unsigned* __restrict__ pool2,
    const int4* __restrict__ seg,
    float* __restrict__ sent,
    float* __restrict__ recv,
    int n_nodes)
{
    int node = blockIdx.x * 4 + (threadIdx.x >> 6);
    int lane = threadIdx.x & 63;
    if (node >= n_nodes) return;

    int4 si = seg[node];

    float accs = 0.f;
    {
        int s = si.x, c = si.y, j = 0;
        for (; j + 8 <= c; j += 8) {
            unsigned e0 = pool2[s+j],   e1 = pool2[s+j+1], e2 = pool2[s+j+2], e3 = pool2[s+j+3];
            unsigned e4 = pool2[s+j+4], e5 = pool2[s+j+5], e6 = pool2[s+j+6], e7 = pool2[s+j+7];
            float v0 = edges[(long)e0 * D + lane];
            float v1 = edges[(long)e1 * D + lane];
            float v2 = edges[(long)e2 * D + lane];
            float v3 = edges[(long)e3 * D + lane];
            float v4 = edges[(long)e4 * D + lane];
            float v5 = edges[(long)e5 * D + lane];
            float v6 = edges[(long)e6 * D + lane];
            float v7 = edges[(long)e7 * D + lane];
            accs += ((v0 + v1) + (v2 + v3)) + ((v4 + v5) + (v6 + v7));
        }
        for (; j + 4 <= c; j += 4) {
            unsigned e0 = pool2[s+j], e1 = pool2[s+j+1], e2 = pool2[s+j+2], e3 = pool2[s+j+3];
            float v0 = edges[(long)e0 * D + lane];
            float v1 = edges[(long)e1 * D + lane];
            float v2 = edges[(long)e2 * D + lane];
            float v3 = edges[(long)e3 * D + lane];
            accs += (v0 + v1) + (v2 + v3);
        }
        for (; j < c; ++j) accs += edges[(long)pool2[s+j] * D + lane];
    }

    float accr = 0.f;
    {
        int s = si.z, c = si.w, j = 0;
        for (; j + 8 <= c; j += 8) {
            unsigned e0 = pool2[s+j],   e1 = pool2[s+j+1], e2 = pool2[s+j+2], e3 = pool2[s+j+3];
            unsigned e4 = pool2[s+j+4], e5 = pool2[s+j+5], e6 = pool2[s+j+6], e7 = pool2[s+j+7];
            float v0 = edges[(long)e0 * D + lane];
            float v1 = edges[(long)e1 * D + lane];
            float v2 = edges[(long)e2 * D + lane];
            float v3 = edges[(long)e3 * D + lane];
            float v4 = edges[(long)e4 * D + lane];
            float v5 = edges[(long)e5 * D + lane];
            float v6 = edges[(long)e6 * D + lane];
            float v7 = edges[(long)e7 * D + lane];
            accr += ((v0 + v1) + (v2 + v3)) + ((v4 + v5) + (v6 + v7));
        }
        for (; j + 4 <= c; j += 4) {
            unsigned e0 = pool2[s+j], e1 = pool2[s+j+1], e2 = pool2[s+j+2], e3 = pool2[s+j+3];
            float v0 = edges[(long)e0 * D + lane];
            float v1 = edges[(long)e1 * D + lane];
            float v2 = edges[(long)e2 * D + lane];
            float v3 = edges[(long)e3 * D + lane];
            accr += (v0 + v1) + (v2 + v3);
        }
        for (; j < c; ++j) accr += edges[(long)pool2[s+j] * D + lane];
    }

    sent[(long)node * D + lane] = accs;
    recv[(long)node * D + lane] = accr;
}

// ---------------------------------------------------------------------------
// per-node MLP (exact f32)
// ---------------------------------------------------------------------------
__global__ __launch_bounds__(256) void mlp_kernel(
    const float* __restrict__ nodes,
    const float* __restrict__ sent,
    const float* __restrict__ recv,
    const float* __restrict__ W1,
    const float* __restrict__ b1,
    const float* __restrict__ W2,
    const float* __restrict__ b2,
    float* __restrict__ out,
    int n)
{
    __shared__ float sW1[IN_DIM * HID];
    __shared__ float sb1[HID];
    __shared__ float sW2[HID * 2];
    __shared__ float sb2[2];

    for (int t = threadIdx.x; t < IN_DIM * HID; t += blockDim.x) sW1[t] = W1[t];
    if (threadIdx.x < HID)     sb1[threadIdx.x] = b1[threadIdx.x];
    if (threadIdx.x < HID * 2) sW2[threadIdx.x] = W2[threadIdx.x];
    if (threadIdx.x < 2)       sb2[threadIdx.x] = b2[threadIdx.x];
    __syncthreads();

    int node = blockIdx.x * blockDim.x + threadIdx.x;
    if (node >= n) return;

    float acc[HID];
#pragma unroll
    for (int j = 0; j < HID; ++j) acc[j] = sb1[j];

#pragma unroll
    for (int part = 0; part < 3; ++part) {
        const float* f = (part == 0 ? nodes : (part == 1 ? sent : recv)) + (long)node * D;
        const float* w = sW1 + part * D * HID;
        for (int k = 0; k < D; k += 4) {
            float4 fv = *reinterpret_cast<const float4*>(f + k);
#pragma unroll
            for (int j = 0; j < HID; ++j) {
                acc[j] += fv.x * w[(k + 0) * HID + j];
                acc[j] += fv.y * w[(k + 1) * HID + j];
                acc[j] += fv.z * w[(k + 2) * HID + j];
                acc[j] += fv.w * w[(k + 3) * HID + j];
            }
        }
    }

    float o0 = sb2[0], o1 = sb2[1];
#pragma unroll
    for (int j = 0; j < HID; ++j) {
        float h = fmaxf(acc[j], 0.f);
        o0 += h * sW2[j * 2 + 0];
        o1 += h * sW2[j * 2 + 1];
    }
    reinterpret_cast<float2*>(out)[node] = make_float2(o0, o1);
}

// ---------------------------------------------------------------------------
extern "C" void kernel_launch(void* const* d_in, const int* in_sizes, int n_in,
                              void* d_out, int out_size, void* d_ws, size_t ws_size,
                              hipStream_t stream) {
    const float* nodes     = (const float*)d_in[0];
    const float* edges     = (const float*)d_in[1];
    const int*   senders   = (const int*)d_in[2];
    const int*   receivers = (const int*)d_in[3];
    const float* W1        = (const float*)d_in[4];
    const float* b1        = (const float*)d_in[5];
    const float* W2        = (const float*)d_in[6];
    const float* b2        = (const float*)d_in[7];
    float* out = (float*)d_out;

    const int  n_nodes = in_sizes[0] / D;      // 100,000
    const long E       = in_sizes[2];          // 3,200,000
    const long total_items = 2 * E;            // 6.4M endpoint records

    const int NB      = (n_nodes + NPB - 1) / NPB;                 // 1563
    const int nblocks = (int)((total_items + CHUNK - 1) / CHUNK);  // 1563

    const size_t sz_sent = (size_t)n_nodes * D * sizeof(float);    // 25.6 MB
    const size_t sz_pool = (size_t)total_items * sizeof(unsigned); // 25.6 MB
    const size_t sz_seg  = (size_t)n_nodes * sizeof(int4);         // 1.6 MB
    const size_t sz_nb   = (size_t)MAXNB * sizeof(int);
    const size_t need    = 2 * sz_sent + 2 * sz_pool + sz_seg + 2 * sz_nb;
    const size_t sz_counts = (size_t)nblocks * NB * sizeof(int);   // 9.8 MB

    char* wp = (char*)d_ws;
    float*    sent  = (float*)wp;           wp += sz_sent;
    float*    recv  = (float*)wp;           wp += sz_sent;
    unsigned* pool  = (unsigned*)wp;        wp += sz_pool;
    unsigned* pool2 = (unsigned*)wp;        wp += sz_pool;
    int4*     seg   = (int4*)wp;            wp += sz_seg;
    int*      tot   = (int*)wp;             wp += sz_nb;
    int*      base  = (int*)wp;
    int*      counts = (int*)sent;          // aliased; dead after scatter_ids

    if (ws_size < need || NB > MAXNB || sz_counts > sz_sent) {
        long n4 = (long)n_nodes * D * 2 / 4;
        zero_ws_kernel<<<2048, 256, 0, stream>>>((float4*)d_ws, n4);
        long total = E * D;
        scatter_kernel<<<(int)((total + 255) / 256), 256, 0, stream>>>(
            edges, senders, receivers, sent, recv, total);
        mlp_kernel<<<(n_nodes + 255) / 256, 256, 0, stream>>>(
            nodes, sent, recv, W1, b1, W2, b2, out, n_nodes);
        return;
    }

    count_kernel<<<nblocks, 256, 0, stream>>>(senders, receivers, counts,
                                              NB, E, total_items);
    colscan_kernel<<<(NB + 255) / 256, 256, 0, stream>>>(counts, tot, NB, nblocks);
    basescan_kernel<<<1, 1024, 0, stream>>>(tot, base, NB);
    scatter_ids_kernel<<<nblocks, 256, 0, stream>>>(senders, receivers, counts,
                                                    base, pool, NB, E, total_items);
    sort_bucket_kernel<<<NB, 256, 0, stream>>>(pool, base, tot, pool2, seg, n_nodes);
    gather_kernel<<<(n_nodes + 3) / 4, 256, 0, stream>>>(edges, pool2, seg,
                                                         sent, recv, n_nodes);
    mlp_kernel<<<(n_nodes + 255) / 256, 256, 0, stream>>>(
        nodes, sent, recv, W1, b1, W2, b2, out, n_nodes);
}

// Round 7
// 553.608 us; speedup vs baseline: 4.8877x; 1.3152x over previous
//
#include <hip/hip_runtime.h>
#include <hip/hip_bf16.h>

#define D      64
#define HID    36
#define IN_DIM 192
#define NPB    64        // nodes per bucket (node >> 6)
#define MAXNB  2048      // max buckets (n_nodes <= 131072)
#define CHUNK  4096      // endpoint records per partition block
#define SLICE  64        // partition-block rows per colscan slice

// ---------------------------------------------------------------------------
__global__ void zero_ws_kernel(float4* __restrict__ p, long n4) {
    long i = (long)blockIdx.x * blockDim.x + threadIdx.x;
    long stride = (long)gridDim.x * blockDim.x;
    float4 z = make_float4(0.f, 0.f, 0.f, 0.f);
    for (; i < n4; i += stride) p[i] = z;
}

// FALLBACK: R0 atomic scatter
__global__ __launch_bounds__(256) void scatter_kernel(
    const float* __restrict__ edges,
    const int* __restrict__ senders,
    const int* __restrict__ receivers,
    float* __restrict__ sent,
    float* __restrict__ recv,
    long total)
{
    long i = (long)blockIdx.x * blockDim.x + threadIdx.x;
    if (i >= total) return;
    long e = i >> 6;
    int  d = (int)(i & 63);
    float v = edges[i];
    unsafeAtomicAdd(&sent[(long)senders[e] * D + d], v);
    unsafeAtomicAdd(&recv[(long)receivers[e] * D + d], v);
}

// ---------------------------------------------------------------------------
// K_a: per-block bucket histogram.
// record i in [0,2E): i<E -> (edge=i, dir=0, node=senders[i])
//                     else  (edge=i-E, dir=1, node=receivers[i-E])
// ---------------------------------------------------------------------------
__global__ __launch_bounds__(256) void count_kernel(
    const int* __restrict__ senders,
    const int* __restrict__ receivers,
    int* __restrict__ counts,          // [nblocks][NB]
    int NB, long E, long total_items)
{
    __shared__ int hist[MAXNB];
    for (int b = threadIdx.x; b < NB; b += 256) hist[b] = 0;
    __syncthreads();

    long start = (long)blockIdx.x * CHUNK;
    long end = start + CHUNK; if (end > total_items) end = total_items;
    for (long i = start + threadIdx.x; i < end; i += 256) {
        int node = (i < E) ? senders[i] : receivers[i - E];
        atomicAdd(&hist[node >> 6], 1);
    }
    __syncthreads();
    int* row = counts + (long)blockIdx.x * NB;
    for (int b = threadIdx.x; b < NB; b += 256) row[b] = hist[b];
}

// K_b1a: within-slice column scan.  grid = (ceil(NB/256), S)
__global__ __launch_bounds__(256) void colscan1_kernel(
    int* __restrict__ counts, int* __restrict__ psum, int NB, int nblocks)
{
    int b = blockIdx.x * 256 + threadIdx.x;
    if (b >= NB) return;
    int s = blockIdx.y;
    int r0 = s * SLICE;
    int r1 = r0 + SLICE; if (r1 > nblocks) r1 = nblocks;
    int run = 0;
    for (int blk = r0; blk < r1; ++blk) {
        long idx = (long)blk * NB + b;
        int c = counts[idx];
        counts[idx] = run;
        run += c;
    }
    psum[(long)s * NB + b] = run;
}

// K_b1b: scan slice sums per column; produce tot.
__global__ __launch_bounds__(256) void colscan2_kernel(
    int* __restrict__ psum, int* __restrict__ tot, int NB, int S)
{
    int b = blockIdx.x * 256 + threadIdx.x;
    if (b >= NB) return;
    int run = 0;
    for (int s = 0; s < S; ++s) {
        long i = (long)s * NB + b;
        int v = psum[i];
        psum[i] = run;
        run += v;
    }
    tot[b] = run;
}

// K_b2: exclusive scan of tot[NB] -> base[NB] (single block)
__global__ __launch_bounds__(1024) void basescan_kernel(
    const int* __restrict__ tot, int* __restrict__ base, int NB)
{
    __shared__ int sA[2][MAXNB];
    int t = threadIdx.x;
    sA[0][t]        = (t < NB) ? tot[t] : 0;
    sA[0][t + 1024] = (t + 1024 < NB) ? tot[t + 1024] : 0;
    __syncthreads();
    int src = 0;
    for (int off = 1; off < MAXNB; off <<= 1) {
        int dst = src ^ 1;
        int i0 = t, i1 = t + 1024;
        sA[dst][i0] = sA[src][i0] + ((i0 >= off) ? sA[src][i0 - off] : 0);
        sA[dst][i1] = sA[src][i1] + ((i1 >= off) ? sA[src][i1 - off] : 0);
        src = dst;
        __syncthreads();
    }
    if (t < NB)        base[t]        = (t == 0) ? 0 : sA[src][t - 1];
    if (t + 1024 < NB) base[t + 1024] = sA[src][t + 1023];
}

// K_c: place records grouped by bucket. rec = edge<<7 | dir<<6 | node_lo
__global__ __launch_bounds__(256) void scatter_ids_kernel(
    const int* __restrict__ senders,
    const int* __restrict__ receivers,
    const int* __restrict__ counts,
    const int* __restrict__ psum,
    const int* __restrict__ base,
    unsigned* __restrict__ pool,
    int NB, long E, long total_items)
{
    __shared__ int cursor[MAXNB];
    const int* row = counts + (long)blockIdx.x * NB;
    const int* srow = psum + (long)(blockIdx.x / SLICE) * NB;
    for (int b = threadIdx.x; b < NB; b += 256)
        cursor[b] = row[b] + srow[b] + base[b];
    __syncthreads();

    long start = (long)blockIdx.x * CHUNK;
    long end = start + CHUNK; if (end > total_items) end = total_items;
    for (long i = start + threadIdx.x; i < end; i += 256) {
        int dir, node; long edge;
        if (i < E) { dir = 0; edge = i;     node = senders[i]; }
        else       { dir = 1; edge = i - E; node = receivers[i - E]; }
        int b = node >> 6;
        int pos = atomicAdd(&cursor[b], 1);
        pool[pos] = ((unsigned)edge << 7) | ((unsigned)dir << 6) | (unsigned)(node & 63);
    }
}

// ---------------------------------------------------------------------------
// K_e: per-bucket counting sort by key = (node_lo<<1)|dir (128 keys).
// Per-wave replicated hist/cursor: each wave owns a contiguous quarter of
// the bucket's records -> zero cross-wave atomic contention.
// ---------------------------------------------------------------------------
__global__ __launch_bounds__(256) void sort_bucket_kernel(
    const unsigned* __restrict__ pool,
    const int* __restrict__ base,
    const int* __restrict__ tot,
    unsigned* __restrict__ pool2,
    int4* __restrict__ seg,
    int n_nodes)
{
    __shared__ int hist[4][128];
    __shared__ int cursor[4][128];
    __shared__ int off[128], comb[128], tmp[128];

    int b = blockIdx.x, tid = threadIdx.x;
    int w = tid >> 6, lane = tid & 63;
    int bstart = base[b], cnt = tot[b];

    ((int*)hist)[tid] = 0;
    ((int*)hist)[tid + 256] = 0;
    __syncthreads();

    int q = (cnt + 3) >> 2;
    int rs = w * q;
    int re = rs + q; if (re > cnt) re = cnt;

    for (int i = rs + lane; i < re; i += 64) {
        unsigned r = pool[bstart + i];
        int key = ((r & 63) << 1) | ((r >> 6) & 1);
        atomicAdd(&hist[w][key], 1);
    }
    __syncthreads();

    if (tid < 128) {
        comb[tid] = hist[0][tid] + hist[1][tid] + hist[2][tid] + hist[3][tid];
        tmp[tid] = comb[tid];
    }
    __syncthreads();
    for (int d = 1; d < 128; d <<= 1) {
        int v = 0;
        if (tid < 128) v = (tid >= d) ? tmp[tid - d] : 0;
        __syncthreads();
        if (tid < 128) tmp[tid] += v;
        __syncthreads();
    }
    if (tid < 128) {
        int o = tmp[tid] - comb[tid];
        off[tid] = o;
        int c0 = o + hist[0][tid];
        int c1 = c0 + hist[1][tid];
        int c2 = c1 + hist[2][tid];
        cursor[0][tid] = o;
        cursor[1][tid] = c0;
        cursor[2][tid] = c1;
        cursor[3][tid] = c2;
    }
    __syncthreads();

    if (tid < 64) {
        int node = b * NPB + tid;
        if (node < n_nodes) {
            seg[node] = make_int4(bstart + off[tid * 2],     comb[tid * 2],
                                  bstart + off[tid * 2 + 1], comb[tid * 2 + 1]);
        }
    }

    for (int i = rs + lane; i < re; i += 64) {
        unsigned r = pool[bstart + i];
        int key = ((r & 63) << 1) | ((r >> 6) & 1);
        int pos = atomicAdd(&cursor[w][key], 1);
        pool2[bstart + pos] = r >> 7;          // bare edge id
    }
}

// ---------------------------------------------------------------------------
// K_f: gather. One wave per node, lane = feature. Register accumulation only.
// ---------------------------------------------------------------------------
__global__ __launch_bounds__(256) void gather_kernel(
    const float* __restrict__ edges,
    const unsigned* __restrict__ pool2,
    const int4* __restrict__ seg,
    float* __restrict__ sent,
    float* __restrict__ recv,
    int n_nodes)
{
    int node = blockIdx.x * 4 + (threadIdx.x >> 6);
    int lane = threadIdx.x & 63;
    if (node >= n_nodes) return;

    int4 si = seg[node];

    float accs = 0.f;
    {
        int s = si.x, c = si.y, j = 0;
        for (; j + 8 <= c; j += 8) {
            unsigned e0 = pool2[s+j],   e1 = pool2[s+j+1], e2 = pool2[s+j+2], e3 = pool2[s+j+3];
            unsigned e4 = pool2[s+j+4], e5 = pool2[s+j+5], e6 = pool2[s+j+6], e7 = pool2[s+j+7];
            float v0 = edges[(long)e0 * D + lane];
            float v1 = edges[(long)e1 * D + lane];
            float v2 = edges[(long)e2 * D + lane];
            float v3 = edges[(long)e3 * D + lane];
            float v4 = edges[(long)e4 * D + lane];
            float v5 = edges[(long)e5 * D + lane];
            float v6 = edges[(long)e6 * D + lane];
            float v7 = edges[(long)e7 * D + lane];
            accs += ((v0 + v1) + (v2 + v3)) + ((v4 + v5) + (v6 + v7));
        }
        for (; j + 4 <= c; j += 4) {
            unsigned e0 = pool2[s+j], e1 = pool2[s+j+1], e2 = pool2[s+j+2], e3 = pool2[s+j+3];
            float v0 = edges[(long)e0 * D + lane];
            float v1 = edges[(long)e1 * D + lane];
            float v2 = edges[(long)e2 * D + lane];
            float v3 = edges[(long)e3 * D + lane];
            accs += (v0 + v1) + (v2 + v3);
        }
        for (; j < c; ++j) accs += edges[(long)pool2[s+j] * D + lane];
    }

    float accr = 0.f;
    {
        int s = si.z, c = si.w, j = 0;
        for (; j + 8 <= c; j += 8) {
            unsigned e0 = pool2[s+j],   e1 = pool2[s+j+1], e2 = pool2[s+j+2], e3 = pool2[s+j+3];
            unsigned e4 = pool2[s+j+4], e5 = pool2[s+j+5], e6 = pool2[s+j+6], e7 = pool2[s+j+7];
            float v0 = edges[(long)e0 * D + lane];
            float v1 = edges[(long)e1 * D + lane];
            float v2 = edges[(long)e2 * D + lane];
            float v3 = edges[(long)e3 * D + lane];
            float v4 = edges[(long)e4 * D + lane];
            float v5 = edges[(long)e5 * D + lane];
            float v6 = edges[(long)e6 * D + lane];
            float v7 = edges[(long)e7 * D + lane];
            accr += ((v0 + v1) + (v2 + v3)) + ((v4 + v5) + (v6 + v7));
        }
        for (; j + 4 <= c; j += 4) {
            unsigned e0 = pool2[s+j], e1 = pool2[s+j+1], e2 = pool2[s+j+2], e3 = pool2[s+j+3];
            float v0 = edges[(long)e0 * D + lane];
            float v1 = edges[(long)e1 * D + lane];
            float v2 = edges[(long)e2 * D + lane];
            float v3 = edges[(long)e3 * D + lane];
            accr += (v0 + v1) + (v2 + v3);
        }
        for (; j < c; ++j) accr += edges[(long)pool2[s+j] * D + lane];
    }

    sent[(long)node * D + lane] = accs;
    recv[(long)node * D + lane] = accr;
}

// ---------------------------------------------------------------------------
// per-node MLP (exact f32)
// ---------------------------------------------------------------------------
__global__ __launch_bounds__(256) void mlp_kernel(
    const float* __restrict__ nodes,
    const float* __restrict__ sent,
    const float* __restrict__ recv,
    const float* __restrict__ W1,
    const float* __restrict__ b1,
    const float* __restrict__ W2,
    const float* __restrict__ b2,
    float* __restrict__ out,
    int n)
{
    __shared__ float sW1[IN_DIM * HID];
    __shared__ float sb1[HID];
    __shared__ float sW2[HID * 2];
    __shared__ float sb2[2];

    for (int t = threadIdx.x; t < IN_DIM * HID; t += blockDim.x) sW1[t] = W1[t];
    if (threadIdx.x < HID)     sb1[threadIdx.x] = b1[threadIdx.x];
    if (threadIdx.x < HID * 2) sW2[threadIdx.x] = W2[threadIdx.x];
    if (threadIdx.x < 2)       sb2[threadIdx.x] = b2[threadIdx.x];
    __syncthreads();

    int node = blockIdx.x * blockDim.x + threadIdx.x;
    if (node >= n) return;

    float acc[HID];
#pragma unroll
    for (int j = 0; j < HID; ++j) acc[j] = sb1[j];

#pragma unroll
    for (int part = 0; part < 3; ++part) {
        const float* f = (part == 0 ? nodes : (part == 1 ? sent : recv)) + (long)node * D;
        const float* w = sW1 + part * D * HID;
        for (int k = 0; k < D; k += 4) {
            float4 fv = *reinterpret_cast<const float4*>(f + k);
#pragma unroll
            for (int j = 0; j < HID; ++j) {
                acc[j] += fv.x * w[(k + 0) * HID + j];
                acc[j] += fv.y * w[(k + 1) * HID + j];
                acc[j] += fv.z * w[(k + 2) * HID + j];
                acc[j] += fv.w * w[(k + 3) * HID + j];
            }
        }
    }

    float o0 = sb2[0], o1 = sb2[1];
#pragma unroll
    for (int j = 0; j < HID; ++j) {
        float h = fmaxf(acc[j], 0.f);
        o0 += h * sW2[j * 2 + 0];
        o1 += h * sW2[j * 2 + 1];
    }
    reinterpret_cast<float2*>(out)[node] = make_float2(o0, o1);
}

// ---------------------------------------------------------------------------
extern "C" void kernel_launch(void* const* d_in, const int* in_sizes, int n_in,
                              void* d_out, int out_size, void* d_ws, size_t ws_size,
                              hipStream_t stream) {
    const float* nodes     = (const float*)d_in[0];
    const float* edges     = (const float*)d_in[1];
    const int*   senders   = (const int*)d_in[2];
    const int*   receivers = (const int*)d_in[3];
    const float* W1        = (const float*)d_in[4];
    const float* b1        = (const float*)d_in[5];
    const float* W2        = (const float*)d_in[6];
    const float* b2        = (const float*)d_in[7];
    float* out = (float*)d_out;

    const int  n_nodes = in_sizes[0] / D;      // 100,000
    const long E       = in_sizes[2];          // 3,200,000
    const long total_items = 2 * E;            // 6.4M endpoint records

    const int NB      = (n_nodes + NPB - 1) / NPB;                 // 1563
    const int nblocks = (int)((total_items + CHUNK - 1) / CHUNK);  // 1563
    const int S       = (nblocks + SLICE - 1) / SLICE;             // 25

    const size_t sz_sent = (size_t)n_nodes * D * sizeof(float);    // 25.6 MB
    const size_t sz_pool = (size_t)total_items * sizeof(unsigned); // 25.6 MB
    const size_t sz_seg  = (size_t)n_nodes * sizeof(int4);         // 1.6 MB
    const size_t sz_nb   = (size_t)MAXNB * sizeof(int);
    const size_t sz_psum = (size_t)S * NB * sizeof(int);           // ~156 KB
    const size_t need    = 2 * sz_sent + 2 * sz_pool + sz_seg + 2 * sz_nb + sz_psum;
    const size_t sz_counts = (size_t)nblocks * NB * sizeof(int);   // 9.8 MB

    char* wp = (char*)d_ws;
    float*    sent  = (float*)wp;           wp += sz_sent;
    float*    recv  = (float*)wp;           wp += sz_sent;
    unsigned* pool  = (unsigned*)wp;        wp += sz_pool;
    unsigned* pool2 = (unsigned*)wp;        wp += sz_pool;
    int4*     seg   = (int4*)wp;            wp += sz_seg;
    int*      tot   = (int*)wp;             wp += sz_nb;
    int*      base  = (int*)wp;             wp += sz_nb;
    int*      psum  = (int*)wp;
    int*      counts = (int*)sent;          // aliased; dead after scatter_ids

    if (ws_size < need || NB > MAXNB || sz_counts > sz_sent) {
        long n4 = (long)n_nodes * D * 2 / 4;
        zero_ws_kernel<<<2048, 256, 0, stream>>>((float4*)d_ws, n4);
        long total = E * D;
        scatter_kernel<<<(int)((total + 255) / 256), 256, 0, stream>>>(
            edges, senders, receivers, sent, recv, total);
        mlp_kernel<<<(n_nodes + 255) / 256, 256, 0, stream>>>(
            nodes, sent, recv, W1, b1, W2, b2, out, n_nodes);
        return;
    }

    count_kernel<<<nblocks, 256, 0, stream>>>(senders, receivers, counts,
                                              NB, E, total_items);
    {
        dim3 g1((NB + 255) / 256, S);
        colscan1_kernel<<<g1, 256, 0, stream>>>(counts, psum, NB, nblocks);
        colscan2_kernel<<<(NB + 255) / 256, 256, 0, stream>>>(psum, tot, NB, S);
    }
    basescan_kernel<<<1, 1024, 0, stream>>>(tot, base, NB);
    scatter_ids_kernel<<<nblocks, 256, 0, stream>>>(senders, receivers, counts,
                                                    psum, base, pool, NB, E, total_items);
    sort_bucket_kernel<<<NB, 256, 0, stream>>>(pool, base, tot, pool2, seg, n_nodes);
    gather_kernel<<<(n_nodes + 3) / 4, 256, 0, stream>>>(edges, pool2, seg,
                                                         sent, recv, n_nodes);
    mlp_kernel<<<(n_nodes + 255) / 256, 256, 0, stream>>>(
        nodes, sent, recv, W1, b1, W2, b2, out, n_nodes);
}

// Round 8
// 546.594 us; speedup vs baseline: 4.9504x; 1.0128x over previous
//
#include <hip/hip_runtime.h>
#include <hip/hip_bf16.h>

#define D      64
#define HID    36
#define IN_DIM 192
#define NPB    64        // nodes per bucket (node >> 6)
#define MAXNB  2048      // max buckets (n_nodes <= 131072)
#define CHUNK  4096      // endpoint records per partition block
#define SLICE  64        // partition-block rows per colscan slice

// ---------------------------------------------------------------------------
__global__ void zero_ws_kernel(float4* __restrict__ p, long n4) {
    long i = (long)blockIdx.x * blockDim.x + threadIdx.x;
    long stride = (long)gridDim.x * blockDim.x;
    float4 z = make_float4(0.f, 0.f, 0.f, 0.f);
    for (; i < n4; i += stride) p[i] = z;
}

// FALLBACK: R0 atomic scatter
__global__ __launch_bounds__(256) void scatter_kernel(
    const float* __restrict__ edges,
    const int* __restrict__ senders,
    const int* __restrict__ receivers,
    float* __restrict__ sent,
    float* __restrict__ recv,
    long total)
{
    long i = (long)blockIdx.x * blockDim.x + threadIdx.x;
    if (i >= total) return;
    long e = i >> 6;
    int  d = (int)(i & 63);
    float v = edges[i];
    unsafeAtomicAdd(&sent[(long)senders[e] * D + d], v);
    unsafeAtomicAdd(&recv[(long)receivers[e] * D + d], v);
}

// ---------------------------------------------------------------------------
// K_a: per-block bucket histogram.
// ---------------------------------------------------------------------------
__global__ __launch_bounds__(256) void count_kernel(
    const int* __restrict__ senders,
    const int* __restrict__ receivers,
    int* __restrict__ counts,          // [nblocks][NB]
    int NB, long E, long total_items)
{
    __shared__ int hist[MAXNB];
    for (int b = threadIdx.x; b < NB; b += 256) hist[b] = 0;
    __syncthreads();

    long start = (long)blockIdx.x * CHUNK;
    long end = start + CHUNK; if (end > total_items) end = total_items;
    for (long i = start + threadIdx.x; i < end; i += 256) {
        int node = (i < E) ? senders[i] : receivers[i - E];
        atomicAdd(&hist[node >> 6], 1);
    }
    __syncthreads();
    int* row = counts + (long)blockIdx.x * NB;
    for (int b = threadIdx.x; b < NB; b += 256) row[b] = hist[b];
}

// K_b1a: within-slice column scan.  grid = (ceil(NB/256), S)
__global__ __launch_bounds__(256) void colscan1_kernel(
    int* __restrict__ counts, int* __restrict__ psum, int NB, int nblocks)
{
    int b = blockIdx.x * 256 + threadIdx.x;
    if (b >= NB) return;
    int s = blockIdx.y;
    int r0 = s * SLICE;
    int r1 = r0 + SLICE; if (r1 > nblocks) r1 = nblocks;
    int run = 0;
    for (int blk = r0; blk < r1; ++blk) {
        long idx = (long)blk * NB + b;
        int c = counts[idx];
        counts[idx] = run;
        run += c;
    }
    psum[(long)s * NB + b] = run;
}

// K_b1b: scan slice sums per column; produce tot.
__global__ __launch_bounds__(256) void colscan2_kernel(
    int* __restrict__ psum, int* __restrict__ tot, int NB, int S)
{
    int b = blockIdx.x * 256 + threadIdx.x;
    if (b >= NB) return;
    int run = 0;
    for (int s = 0; s < S; ++s) {
        long i = (long)s * NB + b;
        int v = psum[i];
        psum[i] = run;
        run += v;
    }
    tot[b] = run;
}

// K_b2: exclusive scan of tot[NB] -> base[NB] (single block)
__global__ __launch_bounds__(1024) void basescan_kernel(
    const int* __restrict__ tot, int* __restrict__ base, int NB)
{
    __shared__ int sA[2][MAXNB];
    int t = threadIdx.x;
    sA[0][t]        = (t < NB) ? tot[t] : 0;
    sA[0][t + 1024] = (t + 1024 < NB) ? tot[t + 1024] : 0;
    __syncthreads();
    int src = 0;
    for (int off = 1; off < MAXNB; off <<= 1) {
        int dst = src ^ 1;
        int i0 = t, i1 = t + 1024;
        sA[dst][i0] = sA[src][i0] + ((i0 >= off) ? sA[src][i0 - off] : 0);
        sA[dst][i1] = sA[src][i1] + ((i1 >= off) ? sA[src][i1 - off] : 0);
        src = dst;
        __syncthreads();
    }
    if (t < NB)        base[t]        = (t == 0) ? 0 : sA[src][t - 1];
    if (t + 1024 < NB) base[t + 1024] = sA[src][t + 1023];
}

// K_c: place records grouped by bucket. rec = edge<<7 | dir<<6 | node_lo
__global__ __launch_bounds__(256) void scatter_ids_kernel(
    const int* __restrict__ senders,
    const int* __restrict__ receivers,
    const int* __restrict__ counts,
    const int* __restrict__ psum,
    const int* __restrict__ base,
    unsigned* __restrict__ pool,
    int NB, long E, long total_items)
{
    __shared__ int cursor[MAXNB];
    const int* row = counts + (long)blockIdx.x * NB;
    const int* srow = psum + (long)(blockIdx.x / SLICE) * NB;
    for (int b = threadIdx.x; b < NB; b += 256)
        cursor[b] = row[b] + srow[b] + base[b];
    __syncthreads();

    long start = (long)blockIdx.x * CHUNK;
    long end = start + CHUNK; if (end > total_items) end = total_items;
    for (long i = start + threadIdx.x; i < end; i += 256) {
        int dir, node; long edge;
        if (i < E) { dir = 0; edge = i;     node = senders[i]; }
        else       { dir = 1; edge = i - E; node = receivers[i - E]; }
        int b = node >> 6;
        int pos = atomicAdd(&cursor[b], 1);
        pool[pos] = ((unsigned)edge << 7) | ((unsigned)dir << 6) | (unsigned)(node & 63);
    }
}

// ---------------------------------------------------------------------------
// K_e: per-bucket counting sort by key = (node_lo<<1)|dir (128 keys).
// Per-wave replicated hist/cursor (no cross-wave contention).
// ---------------------------------------------------------------------------
__global__ __launch_bounds__(256) void sort_bucket_kernel(
    const unsigned* __restrict__ pool,
    const int* __restrict__ base,
    const int* __restrict__ tot,
    unsigned* __restrict__ pool2,
    int4* __restrict__ seg,
    int n_nodes)
{
    __shared__ int hist[4][128];
    __shared__ int cursor[4][128];
    __shared__ int off[128], comb[128], tmp[128];

    int b = blockIdx.x, tid = threadIdx.x;
    int w = tid >> 6, lane = tid & 63;
    int bstart = base[b], cnt = tot[b];

    ((int*)hist)[tid] = 0;
    ((int*)hist)[tid + 256] = 0;
    __syncthreads();

    int q = (cnt + 3) >> 2;
    int rs = w * q;
    int re = rs + q; if (re > cnt) re = cnt;

    for (int i = rs + lane; i < re; i += 64) {
        unsigned r = pool[bstart + i];
        int key = ((r & 63) << 1) | ((r >> 6) & 1);
        atomicAdd(&hist[w][key], 1);
    }
    __syncthreads();

    if (tid < 128) {
        comb[tid] = hist[0][tid] + hist[1][tid] + hist[2][tid] + hist[3][tid];
        tmp[tid] = comb[tid];
    }
    __syncthreads();
    for (int d = 1; d < 128; d <<= 1) {
        int v = 0;
        if (tid < 128) v = (tid >= d) ? tmp[tid - d] : 0;
        __syncthreads();
        if (tid < 128) tmp[tid] += v;
        __syncthreads();
    }
    if (tid < 128) {
        int o = tmp[tid] - comb[tid];
        off[tid] = o;
        int c0 = o + hist[0][tid];
        int c1 = c0 + hist[1][tid];
        int c2 = c1 + hist[2][tid];
        cursor[0][tid] = o;
        cursor[1][tid] = c0;
        cursor[2][tid] = c1;
        cursor[3][tid] = c2;
    }
    __syncthreads();

    if (tid < 64) {
        int node = b * NPB + tid;
        if (node < n_nodes) {
            seg[node] = make_int4(bstart + off[tid * 2],     comb[tid * 2],
                                  bstart + off[tid * 2 + 1], comb[tid * 2 + 1]);
        }
    }

    for (int i = rs + lane; i < re; i += 64) {
        unsigned r = pool[bstart + i];
        int key = ((r & 63) << 1) | ((r >> 6) & 1);
        int pos = atomicAdd(&cursor[w][key], 1);
        pool2[bstart + pos] = r >> 7;          // bare edge id
    }
}

// ---------------------------------------------------------------------------
// K_f: FUSED gather + MLP. One wave per node, lane = feature.
// ids staged in LDS per 128-batch (wave-cooperative load), so the row loop's
// addresses come from ds_read broadcasts -> VMEM queue holds only row loads.
// MLP epilogue in-wave: feats staged in LDS, lanes 0..35 compute h[j]
// (W1 row reads are 144B coalesced, L1-hot), shfl-reduce for 2 outputs.
// ---------------------------------------------------------------------------
__global__ __launch_bounds__(256) void gmlp_kernel(
    const float* __restrict__ edges,
    const unsigned* __restrict__ pool2,
    const int4* __restrict__ seg,
    const float* __restrict__ nodes,
    const float* __restrict__ W1,   // [192][36]
    const float* __restrict__ b1,   // [36]
    const float* __restrict__ W2,   // [36][2]
    const float* __restrict__ b2,   // [2]
    float* __restrict__ out,        // [n][2]
    int n_nodes)
{
    __shared__ unsigned sids[4][128];
    __shared__ float sfeat[4][IN_DIM];

    int w = threadIdx.x >> 6, lane = threadIdx.x & 63;
    int node = blockIdx.x * 4 + w;
    if (node >= n_nodes) return;

    int4 si = seg[node];

    float acc2[2];
#pragma unroll
    for (int dir = 0; dir < 2; ++dir) {
        int s = dir ? si.z : si.x;
        int c = dir ? si.w : si.y;
        float acc = 0.f;
        for (int b0 = 0; b0 < c; b0 += 128) {
            int m = c - b0; if (m > 128) m = 128;
            // cooperative id stage (wave-lockstep; compiler inserts lgkm waits)
            if (lane < m)      sids[w][lane]      = pool2[s + b0 + lane];
            if (64 + lane < m) sids[w][64 + lane] = pool2[s + b0 + 64 + lane];
            int t = 0;
            for (; t + 8 <= m; t += 8) {
                unsigned e0 = sids[w][t],     e1 = sids[w][t + 1];
                unsigned e2 = sids[w][t + 2], e3 = sids[w][t + 3];
                unsigned e4 = sids[w][t + 4], e5 = sids[w][t + 5];
                unsigned e6 = sids[w][t + 6], e7 = sids[w][t + 7];
                float v0 = edges[(long)e0 * D + lane];
                float v1 = edges[(long)e1 * D + lane];
                float v2 = edges[(long)e2 * D + lane];
                float v3 = edges[(long)e3 * D + lane];
                float v4 = edges[(long)e4 * D + lane];
                float v5 = edges[(long)e5 * D + lane];
                float v6 = edges[(long)e6 * D + lane];
                float v7 = edges[(long)e7 * D + lane];
                acc += ((v0 + v1) + (v2 + v3)) + ((v4 + v5) + (v6 + v7));
            }
            for (; t + 4 <= m; t += 4) {
                unsigned e0 = sids[w][t],     e1 = sids[w][t + 1];
                unsigned e2 = sids[w][t + 2], e3 = sids[w][t + 3];
                float v0 = edges[(long)e0 * D + lane];
                float v1 = edges[(long)e1 * D + lane];
                float v2 = edges[(long)e2 * D + lane];
                float v3 = edges[(long)e3 * D + lane];
                acc += (v0 + v1) + (v2 + v3);
            }
            for (; t < m; ++t) acc += edges[(long)sids[w][t] * D + lane];
        }
        acc2[dir] = acc;
    }

    // stage feats = [nodes | sent | recv] for this node
    float nf = nodes[(long)node * D + lane];
    sfeat[w][lane]       = nf;
    sfeat[w][64 + lane]  = acc2[0];
    sfeat[w][128 + lane] = acc2[1];

    // MLP hidden: lanes 0..35 each compute one h[j]
    float h = 0.f;
    if (lane < HID) {
        float h0 = 0.f, h1 = 0.f, h2 = 0.f, h3 = 0.f;
        for (int k = 0; k < IN_DIM; k += 4) {
            h0 += sfeat[w][k]     * W1[(k)     * HID + lane];
            h1 += sfeat[w][k + 1] * W1[(k + 1) * HID + lane];
            h2 += sfeat[w][k + 2] * W1[(k + 2) * HID + lane];
            h3 += sfeat[w][k + 3] * W1[(k + 3) * HID + lane];
        }
        h = fmaxf(b1[lane] + ((h0 + h1) + (h2 + h3)), 0.f);
    }
    float p0 = (lane < HID) ? h * W2[lane * 2 + 0] : 0.f;
    float p1 = (lane < HID) ? h * W2[lane * 2 + 1] : 0.f;
#pragma unroll
    for (int off = 32; off; off >>= 1) {
        p0 += __shfl_down(p0, off, 64);
        p1 += __shfl_down(p1, off, 64);
    }
    if (lane == 0)
        reinterpret_cast<float2*>(out)[node] = make_float2(p0 + b2[0], p1 + b2[1]);
}

// ---------------------------------------------------------------------------
// per-node MLP (fallback path only)
// ---------------------------------------------------------------------------
__global__ __launch_bounds__(256) void mlp_kernel(
    const float* __restrict__ nodes,
    const float* __restrict__ sent,
    const float* __restrict__ recv,
    const float* __restrict__ W1,
    const float* __restrict__ b1,
    const float* __restrict__ W2,
    const float* __restrict__ b2,
    float* __restrict__ out,
    int n)
{
    __shared__ float sW1[IN_DIM * HID];
    __shared__ float sb1[HID];
    __shared__ float sW2[HID * 2];
    __shared__ float sb2[2];

    for (int t = threadIdx.x; t < IN_DIM * HID; t += blockDim.x) sW1[t] = W1[t];
    if (threadIdx.x < HID)     sb1[threadIdx.x] = b1[threadIdx.x];
    if (threadIdx.x < HID * 2) sW2[threadIdx.x] = W2[threadIdx.x];
    if (threadIdx.x < 2)       sb2[threadIdx.x] = b2[threadIdx.x];
    __syncthreads();

    int node = blockIdx.x * blockDim.x + threadIdx.x;
    if (node >= n) return;

    float acc[HID];
#pragma unroll
    for (int j = 0; j < HID; ++j) acc[j] = sb1[j];

#pragma unroll
    for (int part = 0; part < 3; ++part) {
        const float* f = (part == 0 ? nodes : (part == 1 ? sent : recv)) + (long)node * D;
        const float* wgt = sW1 + part * D * HID;
        for (int k = 0; k < D; k += 4) {
            float4 fv = *reinterpret_cast<const float4*>(f + k);
#pragma unroll
            for (int j = 0; j < HID; ++j) {
                acc[j] += fv.x * wgt[(k + 0) * HID + j];
                acc[j] += fv.y * wgt[(k + 1) * HID + j];
                acc[j] += fv.z * wgt[(k + 2) * HID + j];
                acc[j] += fv.w * wgt[(k + 3) * HID + j];
            }
        }
    }

    float o0 = sb2[0], o1 = sb2[1];
#pragma unroll
    for (int j = 0; j < HID; ++j) {
        float h = fmaxf(acc[j], 0.f);
        o0 += h * sW2[j * 2 + 0];
        o1 += h * sW2[j * 2 + 1];
    }
    reinterpret_cast<float2*>(out)[node] = make_float2(o0, o1);
}

// ---------------------------------------------------------------------------
extern "C" void kernel_launch(void* const* d_in, const int* in_sizes, int n_in,
                              void* d_out, int out_size, void* d_ws, size_t ws_size,
                              hipStream_t stream) {
    const float* nodes     = (const float*)d_in[0];
    const float* edges     = (const float*)d_in[1];
    const int*   senders   = (const int*)d_in[2];
    const int*   receivers = (const int*)d_in[3];
    const float* W1        = (const float*)d_in[4];
    const float* b1        = (const float*)d_in[5];
    const float* W2        = (const float*)d_in[6];
    const float* b2        = (const float*)d_in[7];
    float* out = (float*)d_out;

    const int  n_nodes = in_sizes[0] / D;      // 100,000
    const long E       = in_sizes[2];          // 3,200,000
    const long total_items = 2 * E;            // 6.4M endpoint records

    const int NB      = (n_nodes + NPB - 1) / NPB;                 // 1563
    const int nblocks = (int)((total_items + CHUNK - 1) / CHUNK);  // 1563
    const int S       = (nblocks + SLICE - 1) / SLICE;             // 25

    const size_t sz_sent = (size_t)n_nodes * D * sizeof(float);    // 25.6 MB
    const size_t sz_pool = (size_t)total_items * sizeof(unsigned); // 25.6 MB
    const size_t sz_seg  = (size_t)n_nodes * sizeof(int4);         // 1.6 MB
    const size_t sz_nb   = (size_t)MAXNB * sizeof(int);
    const size_t sz_psum = (size_t)S * NB * sizeof(int);           // ~156 KB
    const size_t need    = 2 * sz_sent + 2 * sz_pool + sz_seg + 2 * sz_nb + sz_psum;
    const size_t sz_counts = (size_t)nblocks * NB * sizeof(int);   // 9.8 MB

    char* wp = (char*)d_ws;
    float*    sent  = (float*)wp;           wp += sz_sent;
    float*    recv  = (float*)wp;           wp += sz_sent;
    unsigned* pool  = (unsigned*)wp;        wp += sz_pool;
    unsigned* pool2 = (unsigned*)wp;        wp += sz_pool;
    int4*     seg   = (int4*)wp;            wp += sz_seg;
    int*      tot   = (int*)wp;             wp += sz_nb;
    int*      base  = (int*)wp;             wp += sz_nb;
    int*      psum  = (int*)wp;
    int*      counts = (int*)sent;          // aliased; dead after scatter_ids

    if (ws_size < need || NB > MAXNB || sz_counts > sz_sent) {
        long n4 = (long)n_nodes * D * 2 / 4;
        zero_ws_kernel<<<2048, 256, 0, stream>>>((float4*)d_ws, n4);
        long total = E * D;
        scatter_kernel<<<(int)((total + 255) / 256), 256, 0, stream>>>(
            edges, senders, receivers, sent, recv, total);
        mlp_kernel<<<(n_nodes + 255) / 256, 256, 0, stream>>>(
            nodes, sent, recv, W1, b1, W2, b2, out, n_nodes);
        return;
    }

    count_kernel<<<nblocks, 256, 0, stream>>>(senders, receivers, counts,
                                              NB, E, total_items);
    {
        dim3 g1((NB + 255) / 256, S);
        colscan1_kernel<<<g1, 256, 0, stream>>>(counts, psum, NB, nblocks);
        colscan2_kernel<<<(NB + 255) / 256, 256, 0, stream>>>(psum, tot, NB, S);
    }
    basescan_kernel<<<1, 1024, 0, stream>>>(tot, base, NB);
    scatter_ids_kernel<<<nblocks, 256, 0, stream>>>(senders, receivers, counts,
                                                    psum, base, pool, NB, E, total_items);
    sort_bucket_kernel<<<NB, 256, 0, stream>>>(pool, base, tot, pool2, seg, n_nodes);
    gmlp_kernel<<<(n_nodes + 3) / 4, 256, 0, stream>>>(edges, pool2, seg, nodes,
                                                       W1, b1, W2, b2, out, n_nodes);
}